// Round 10
// baseline (356.237 us; speedup 1.0000x reference)
//
#include <hip/hip_runtime.h>

#define VOL   2097152          // 128*128*128
#define TBL   4194304          // BATCH * VOL
#define D1D2  16384
#define DD2   128
#define TILE  128
#define ZOFF  (-40960)         // byte offset (from fbf) of the 128B zero row in wbf slack

typedef __bf16 bf16_t;
typedef bf16_t bf16x8 __attribute__((ext_vector_type(8)));
typedef float  floatx4 __attribute__((ext_vector_type(4)));

// ---------------- fused prep kernel ----------------
// block roles: [0, tblB) build table; [tblB, tblB+432) weight cvt;
//              [tblB+432, ...) feature cvt (original order) + zero-row init.
// table must be memset to -1 before this dispatch (stream-ordered).

__global__ __launch_bounds__(256) void prep_k(const float* __restrict__ f,
                                              const float* __restrict__ w,
                                              const int* __restrict__ idx,
                                              int* __restrict__ table,
                                              bf16_t* __restrict__ wb,
                                              bf16_t* __restrict__ fb, int n) {
    const int b = blockIdx.x;
    const int tblB = (n + 255) >> 8;
    if (b < tblB) {
        int t = b * 256 + threadIdx.x;
        if (t < n) {
            int4 c = ((const int4*)idx)[t];                 // b, i0, i1, i2
            int p = ((c.x * 128 + c.y) * 128 + c.z) * 128 + c.w;
            table[p] = t;                                   // original voxel id
        }
    } else if (b < tblB + 432) {
        int t = (b - tblB) * 256 + threadIdx.x;
        if (t < 27 * 64 * 64) {                             // [co][27][ci] -> [k][co][ci]
            int ci = t & 63, co = (t >> 6) & 63, k = t >> 12;
            wb[t] = (bf16_t)w[(co * 27 + k) * 64 + ci];
        }
    } else {
        int t = (b - tblB - 432) * 256 + threadIdx.x;       // unit = (voxel, 8-ch)
        int pos = t >> 3, c = (t & 7) * 8;
        if (pos < n) {
            const float* src = f + (size_t)pos * 64 + c;
            float4 a  = *(const float4*)src;
            float4 b2 = *(const float4*)(src + 4);
            bf16x8 o = { (bf16_t)a.x,  (bf16_t)a.y,  (bf16_t)a.z,  (bf16_t)a.w,
                         (bf16_t)b2.x, (bf16_t)b2.y, (bf16_t)b2.z, (bf16_t)b2.w };
            *(bf16x8*)(fb + (size_t)pos * 64 + c) = o;
        } else if (pos == n) {
            // zero row for missing neighbors: 128B in wbf slack, 8 thr x 16B
            bf16x8 z = {};
            *(bf16x8*)(wb + 110592 + c) = z;                // 110592 bf16 = byte 221184
        }
    }
}

// ---------------- main conv kernel (branch-free, 3-deep pipelined) ----------------
// block = 256 thr = 4 waves; tile = 128 voxels x 64 out-ch
// wave w: wc = w&1 -> co half; wv = w>>1 -> voxel half. 2 m-tiles x 4 n-groups x 2 k.
// s_off holds BYTE offsets into fbf; misses (and pad taps 27-28) point at a 128B
// zero row (ZOFF) -> gather loads and MFMAs fully unconditional.
// 3-deep rotating register pipeline (bA/bB/bC, aA/aB/aC): loads for tap k+2
// issue before MFMA(k), hiding ~650cy L3 gather latency under ~2 taps of work.
// __launch_bounds__(256, 2): VGPR budget 256. Round-4 lesson: without the
// waves-per-EU hint the scheduler targets 8 waves/SIMD (<=64 VGPR) and SINKS
// every load next to its use -> 12 serialized round-trips/tap -> 204 us.
// Round-2 lesson: (256,4) clamps to 64 VGPR and spills 8 GB to scratch.
// mfma_f32_16x16x32_bf16: D col=lane&15, row=(lane>>4)*4+reg (m89/m91-verified)

#define LOADB(KK, B) {                                                         \
    const int* sr = &s_off[(KK) * TILE + nrow];                                \
    int o0 = sr[0], o1 = sr[16], o2 = sr[32], o3 = sr[48];                     \
    B[0] = *(const bf16x8*)(fB_ + o0); B[1] = *(const bf16x8*)(fB_ + o0 + 64); \
    B[2] = *(const bf16x8*)(fB_ + o1); B[3] = *(const bf16x8*)(fB_ + o1 + 64); \
    B[4] = *(const bf16x8*)(fB_ + o2); B[5] = *(const bf16x8*)(fB_ + o2 + 64); \
    B[6] = *(const bf16x8*)(fB_ + o3); B[7] = *(const bf16x8*)(fB_ + o3 + 64); \
}

#define LOADA(KK, A) {                                                         \
    const bf16_t* wk = wbase + (size_t)(KK) * 4096;                            \
    A[0] = *(const bf16x8*)(wk);        A[1] = *(const bf16x8*)(wk + 32);      \
    A[2] = *(const bf16x8*)(wk + 1024); A[3] = *(const bf16x8*)(wk + 1056);    \
}

#define DOMFMA(A, B) {                                                         \
    _Pragma("unroll")                                                          \
    for (int g = 0; g < 4; ++g) {                                              \
        acc[0][g] = __builtin_amdgcn_mfma_f32_16x16x32_bf16(A[0], B[2*g],   acc[0][g], 0, 0, 0); \
        acc[0][g] = __builtin_amdgcn_mfma_f32_16x16x32_bf16(A[1], B[2*g+1], acc[0][g], 0, 0, 0); \
        acc[1][g] = __builtin_amdgcn_mfma_f32_16x16x32_bf16(A[2], B[2*g],   acc[1][g], 0, 0, 0); \
        acc[1][g] = __builtin_amdgcn_mfma_f32_16x16x32_bf16(A[3], B[2*g+1], acc[1][g], 0, 0, 0); \
    }                                                                          \
}

__global__ __launch_bounds__(256, 2) void conv_k(
        const bf16_t* __restrict__ fb, const bf16_t* __restrict__ wb,
        const int* __restrict__ table, const int* __restrict__ idx,
        const float* __restrict__ bias, float* __restrict__ out, int n)
{
    __shared__ int s_pkd[TILE];
    __shared__ int s_shift[32];
    __shared__ int s_off[29 * TILE];   // BYTE offsets into fbf; taps 27-28 = ZOFF pad

    const int t    = threadIdx.x;
    const int tile = blockIdx.x * TILE;

    if (t < 32) {
        int k0 = t / 9, k1 = (t / 3) % 3, k2 = t % 3;
        s_shift[t] = (t < 27) ? ((k0 - 1) * D1D2 + (k1 - 1) * DD2 + (k2 - 1)) : 0;
    }
    if (t < TILE) {
        int vn = tile + t;
        if (vn < n) {
            int4 c = ((const int4*)idx)[vn];
            s_pkd[t] = ((c.x * 128 + c.y) * 128 + c.z) * 128 + c.w;
        } else {
            s_pkd[t] = (int)0xC0000000;   // sentinel: all taps miss
        }
    }
    __syncthreads();

    for (int u = t; u < 29 * TILE; u += 256) {
        int k  = u >> 7;                  // TILE == 128
        int r  = u & (TILE - 1);
        int np = s_pkd[r] + s_shift[k];
        int v  = (k < 27 && np >= 0 && np < TBL) ? table[np] : -1;
        s_off[u] = (v >= 0) ? (v << 7) : ZOFF;   // byte offset of feature row
    }

    const int lane = t & 63;
    const int w    = t >> 6;
    const int wc   = w & 1;               // co half
    const int wv   = w >> 1;              // voxel half
    const int l15  = lane & 15;
    const int q    = lane >> 4;

    __syncthreads();                      // s_off ready — LAST barrier in kernel

    // per-lane bases: fold q*16 bytes into feature base; A: co=wc*32+l15, ci=q*8
    const char*   fB_   = (const char*)fb + q * 16;
    const bf16_t* wbase = wb + (size_t)(wc * 32 + l15) * 64 + q * 8;
    const int     nrow  = wv * 64 + l15;  // this lane's voxel row within tile

    floatx4 acc[2][4] = {};
    bf16x8 bA[8], bB[8], bC[8], aA[4], aB[4], aC[4];

    LOADB(0, bA); LOADA(0, aA);
    LOADB(1, bB); LOADA(1, aB);

    #pragma unroll
    for (int k = 0; k < 27; k += 3) {     // 9 iters x 3 taps, static rotation
        LOADB(k + 2, bC); LOADA(k + 2, aC);
        DOMFMA(aA, bA);                   // tap k
        LOADB(k + 3, bA); LOADA(k + 3, aA);
        DOMFMA(aB, bB);                   // tap k+1
        LOADB(k + 4, bB); LOADA(k + 4, aB);
        DOMFMA(aC, bC);                   // tap k+2
    }
    // taps 27/28 loads hit ZOFF pad rows / wbf slack — issued but never used

    // epilogue: co = wc*32 + m*16 + q*4 + reg, voxel = tile + wv*64 + g*16 + l15
    const float4 bs0 = *(const float4*)&bias[wc * 32 + q * 4];
    const float4 bs1 = *(const float4*)&bias[wc * 32 + 16 + q * 4];
    #pragma unroll
    for (int g = 0; g < 4; ++g) {
        int vn = tile + wv * 64 + g * 16 + l15;
        if (vn < n) {
            float4 o0, o1;
            o0.x = acc[0][g][0] + bs0.x;
            o0.y = acc[0][g][1] + bs0.y;
            o0.z = acc[0][g][2] + bs0.z;
            o0.w = acc[0][g][3] + bs0.w;
            o1.x = acc[1][g][0] + bs1.x;
            o1.y = acc[1][g][1] + bs1.y;
            o1.z = acc[1][g][2] + bs1.z;
            o1.w = acc[1][g][3] + bs1.w;
            float* dst = &out[(size_t)vn * 64 + wc * 32 + q * 4];
            *(float4*)dst        = o0;
            *(float4*)(dst + 16) = o1;
        }
    }
}

// ---------------- launch ----------------

extern "C" void kernel_launch(void* const* d_in, const int* in_sizes, int n_in,
                              void* d_out, int out_size, void* d_ws, size_t ws_size,
                              hipStream_t stream) {
    const float* feat = (const float*)d_in[0];
    const float* wgt  = (const float*)d_in[1];
    const float* bias = (const float*)d_in[2];
    const int*   idx  = (const int*)d_in[3];
    float* out = (float*)d_out;

    const int n = in_sizes[0] / 64;          // active voxels

    // ws layout (round-1 proven, 50.6 MB): [table 16MB][wbf 256KB][fbf 33.5MB]
    // zero row lives in wbf slack: byte 221184..221312 (= fbf + ZOFF)
    char* ws = (char*)d_ws;
    int*    table = (int*)ws;
    bf16_t* wbf   = (bf16_t*)(ws + (size_t)TBL * 4);
    bf16_t* fbf   = (bf16_t*)(ws + (size_t)TBL * 4 + 262144);

    hipMemsetAsync(table, 0xFF, (size_t)TBL * 4, stream);   // all -1

    int tblB = (n + 255) >> 8;
    int fB   = (n * 8 + 255) >> 8;
    // +1 block: zero-row init rides the feature section (pos == n)
    prep_k<<<tblB + 432 + fB + 1, 256, 0, stream>>>(feat, wgt, idx, table, wbf, fbf, n);

    conv_k<<<(n + TILE - 1) / TILE, 256, 0, stream>>>(fbf, wbf, table, idx, bias, out, n);
}

// Round 11
// 307.404 us; speedup vs baseline: 1.1589x; 1.1589x over previous
//
#include <hip/hip_runtime.h>

#define VOL   2097152          // 128*128*128
#define TBL   4194304          // BATCH * VOL
#define D1D2  16384
#define DD2   128
#define TILE  128
#define ZOFF  (-40960)         // byte offset (from fbf) of the 128B zero row in wbf slack

typedef __bf16 bf16_t;
typedef bf16_t bf16x8 __attribute__((ext_vector_type(8)));
typedef float  floatx4 __attribute__((ext_vector_type(4)));

// ---------------- fused prep kernel ----------------
// block roles: [0, tblB) build table; [tblB, tblB+432) weight cvt;
//              [tblB+432, ...) feature cvt (original order) + zero-row init.
// table must be memset to -1 before this dispatch (stream-ordered).

__global__ __launch_bounds__(256) void prep_k(const float* __restrict__ f,
                                              const float* __restrict__ w,
                                              const int* __restrict__ idx,
                                              int* __restrict__ table,
                                              bf16_t* __restrict__ wb,
                                              bf16_t* __restrict__ fb, int n) {
    const int b = blockIdx.x;
    const int tblB = (n + 255) >> 8;
    if (b < tblB) {
        int t = b * 256 + threadIdx.x;
        if (t < n) {
            int4 c = ((const int4*)idx)[t];                 // b, i0, i1, i2
            int p = ((c.x * 128 + c.y) * 128 + c.z) * 128 + c.w;
            table[p] = t;                                   // original voxel id
        }
    } else if (b < tblB + 432) {
        int t = (b - tblB) * 256 + threadIdx.x;
        if (t < 27 * 64 * 64) {                             // [co][27][ci] -> [k][co][ci]
            int ci = t & 63, co = (t >> 6) & 63, k = t >> 12;
            wb[t] = (bf16_t)w[(co * 27 + k) * 64 + ci];
        }
    } else {
        int t = (b - tblB - 432) * 256 + threadIdx.x;       // unit = (voxel, 8-ch)
        int pos = t >> 3, c = (t & 7) * 8;
        if (pos < n) {
            const float* src = f + (size_t)pos * 64 + c;
            float4 a  = *(const float4*)src;
            float4 b2 = *(const float4*)(src + 4);
            bf16x8 o = { (bf16_t)a.x,  (bf16_t)a.y,  (bf16_t)a.z,  (bf16_t)a.w,
                         (bf16_t)b2.x, (bf16_t)b2.y, (bf16_t)b2.z, (bf16_t)b2.w };
            *(bf16x8*)(fb + (size_t)pos * 64 + c) = o;
        } else if (pos == n) {
            // zero row for missing neighbors: 128B in wbf slack, 8 thr x 16B
            bf16x8 z = {};
            *(bf16x8*)(wb + 110592 + c) = z;                // 110592 bf16 = byte 221184
        }
    }
}

// ---------------- main conv kernel (branch-free, 3-deep, SCHED-PINNED) ----------------
// block = 256 thr = 4 waves; tile = 128 voxels x 64 out-ch
// wave w: wc = w&1 -> co half; wv = w>>1 -> voxel half. 2 m-tiles x 4 n-groups x 2 k.
// s_off holds BYTE offsets into fbf; misses (and pad taps 27-28) -> 128B zero row.
// 3-deep rotating register pipeline (bA/bB/bC, aA/aB/aC) with
// __builtin_amdgcn_sched_barrier(0) at EVERY cluster boundary: round-10 proved
// (VGPR_Count=44) that without fences the pre-RA scheduler sinks all loads next
// to their uses chasing occupancy, serializing ~650cy L3 round-trips (259 us).
// Fences pin {LOADs}|{MFMA} cluster order; scheduler stays free inside clusters;
// compiler then auto-emits counted vmcnt (~24) before each MFMA cluster.
// __launch_bounds__(256,2): VGPR cap 256 (demand ~200, no spill).
// mfma_f32_16x16x32_bf16: D col=lane&15, row=(lane>>4)*4+reg (m89/m91-verified)

#define LOADB(KK, B) {                                                         \
    const int* sr = &s_off[(KK) * TILE + nrow];                                \
    int o0 = sr[0], o1 = sr[16], o2 = sr[32], o3 = sr[48];                     \
    B[0] = *(const bf16x8*)(fB_ + o0); B[1] = *(const bf16x8*)(fB_ + o0 + 64); \
    B[2] = *(const bf16x8*)(fB_ + o1); B[3] = *(const bf16x8*)(fB_ + o1 + 64); \
    B[4] = *(const bf16x8*)(fB_ + o2); B[5] = *(const bf16x8*)(fB_ + o2 + 64); \
    B[6] = *(const bf16x8*)(fB_ + o3); B[7] = *(const bf16x8*)(fB_ + o3 + 64); \
}

#define LOADA(KK, A) {                                                         \
    const bf16_t* wk = wbase + (size_t)(KK) * 4096;                            \
    A[0] = *(const bf16x8*)(wk);        A[1] = *(const bf16x8*)(wk + 32);      \
    A[2] = *(const bf16x8*)(wk + 1024); A[3] = *(const bf16x8*)(wk + 1056);    \
}

#define DOMFMA(A, B) {                                                         \
    _Pragma("unroll")                                                          \
    for (int g = 0; g < 4; ++g) {                                              \
        acc[0][g] = __builtin_amdgcn_mfma_f32_16x16x32_bf16(A[0], B[2*g],   acc[0][g], 0, 0, 0); \
        acc[0][g] = __builtin_amdgcn_mfma_f32_16x16x32_bf16(A[1], B[2*g+1], acc[0][g], 0, 0, 0); \
        acc[1][g] = __builtin_amdgcn_mfma_f32_16x16x32_bf16(A[2], B[2*g],   acc[1][g], 0, 0, 0); \
        acc[1][g] = __builtin_amdgcn_mfma_f32_16x16x32_bf16(A[3], B[2*g+1], acc[1][g], 0, 0, 0); \
    }                                                                          \
}

#define SB() __builtin_amdgcn_sched_barrier(0)

__global__ __launch_bounds__(256, 2) void conv_k(
        const bf16_t* __restrict__ fb, const bf16_t* __restrict__ wb,
        const int* __restrict__ table, const int* __restrict__ idx,
        const float* __restrict__ bias, float* __restrict__ out, int n)
{
    __shared__ int s_pkd[TILE];
    __shared__ int s_shift[32];
    __shared__ int s_off[29 * TILE];   // BYTE offsets into fbf; taps 27-28 = ZOFF pad

    const int t    = threadIdx.x;
    const int tile = blockIdx.x * TILE;

    if (t < 32) {
        int k0 = t / 9, k1 = (t / 3) % 3, k2 = t % 3;
        s_shift[t] = (t < 27) ? ((k0 - 1) * D1D2 + (k1 - 1) * DD2 + (k2 - 1)) : 0;
    }
    if (t < TILE) {
        int vn = tile + t;
        if (vn < n) {
            int4 c = ((const int4*)idx)[vn];
            s_pkd[t] = ((c.x * 128 + c.y) * 128 + c.z) * 128 + c.w;
        } else {
            s_pkd[t] = (int)0xC0000000;   // sentinel: all taps miss
        }
    }
    __syncthreads();

    for (int u = t; u < 29 * TILE; u += 256) {
        int k  = u >> 7;                  // TILE == 128
        int r  = u & (TILE - 1);
        int np = s_pkd[r] + s_shift[k];
        int v  = (k < 27 && np >= 0 && np < TBL) ? table[np] : -1;
        s_off[u] = (v >= 0) ? (v << 7) : ZOFF;   // byte offset of feature row
    }

    const int lane = t & 63;
    const int w    = t >> 6;
    const int wc   = w & 1;               // co half
    const int wv   = w >> 1;              // voxel half
    const int l15  = lane & 15;
    const int q    = lane >> 4;

    __syncthreads();                      // s_off ready — LAST barrier in kernel

    // per-lane bases: fold q*16 bytes into feature base; A: co=wc*32+l15, ci=q*8
    const char*   fB_   = (const char*)fb + q * 16;
    const bf16_t* wbase = wb + (size_t)(wc * 32 + l15) * 64 + q * 8;
    const int     nrow  = wv * 64 + l15;  // this lane's voxel row within tile

    floatx4 acc[2][4] = {};
    bf16x8 bA[8], bB[8], bC[8], aA[4], aB[4], aC[4];

    LOADB(0, bA); LOADA(0, aA);
    LOADB(1, bB); LOADA(1, aB);
    SB();

    #pragma unroll
    for (int k = 0; k < 27; k += 3) {     // 9 iters x 3 taps, static rotation
        LOADB(k + 2, bC); LOADA(k + 2, aC);
        SB();
        DOMFMA(aA, bA);                   // tap k (waits on loads from 2 phases ago)
        SB();
        LOADB(k + 3, bA); LOADA(k + 3, aA);
        SB();
        DOMFMA(aB, bB);                   // tap k+1
        SB();
        LOADB(k + 4, bB); LOADA(k + 4, aB);
        SB();
        DOMFMA(aC, bC);                   // tap k+2
        SB();
    }
    // taps 27/28 loads hit ZOFF pad rows / wbf slack — issued but never consumed

    // epilogue: co = wc*32 + m*16 + q*4 + reg, voxel = tile + wv*64 + g*16 + l15
    const float4 bs0 = *(const float4*)&bias[wc * 32 + q * 4];
    const float4 bs1 = *(const float4*)&bias[wc * 32 + 16 + q * 4];
    #pragma unroll
    for (int g = 0; g < 4; ++g) {
        int vn = tile + wv * 64 + g * 16 + l15;
        if (vn < n) {
            float4 o0, o1;
            o0.x = acc[0][g][0] + bs0.x;
            o0.y = acc[0][g][1] + bs0.y;
            o0.z = acc[0][g][2] + bs0.z;
            o0.w = acc[0][g][3] + bs0.w;
            o1.x = acc[1][g][0] + bs1.x;
            o1.y = acc[1][g][1] + bs1.y;
            o1.z = acc[1][g][2] + bs1.z;
            o1.w = acc[1][g][3] + bs1.w;
            float* dst = &out[(size_t)vn * 64 + wc * 32 + q * 4];
            *(float4*)dst        = o0;
            *(float4*)(dst + 16) = o1;
        }
    }
}

// ---------------- launch ----------------

extern "C" void kernel_launch(void* const* d_in, const int* in_sizes, int n_in,
                              void* d_out, int out_size, void* d_ws, size_t ws_size,
                              hipStream_t stream) {
    const float* feat = (const float*)d_in[0];
    const float* wgt  = (const float*)d_in[1];
    const float* bias = (const float*)d_in[2];
    const int*   idx  = (const int*)d_in[3];
    float* out = (float*)d_out;

    const int n = in_sizes[0] / 64;          // active voxels

    // ws layout (round-1 proven, 50.6 MB): [table 16MB][wbf 256KB][fbf 33.5MB]
    // zero row lives in wbf slack: byte 221184..221312 (= fbf + ZOFF)
    char* ws = (char*)d_ws;
    int*    table = (int*)ws;
    bf16_t* wbf   = (bf16_t*)(ws + (size_t)TBL * 4);
    bf16_t* fbf   = (bf16_t*)(ws + (size_t)TBL * 4 + 262144);

    hipMemsetAsync(table, 0xFF, (size_t)TBL * 4, stream);   // all -1

    int tblB = (n + 255) >> 8;
    int fB   = (n * 8 + 255) >> 8;
    // +1 block: zero-row init rides the feature section (pos == n)
    prep_k<<<tblB + 432 + fB + 1, 256, 0, stream>>>(feat, wgt, idx, table, wbf, fbf, n);

    conv_k<<<(n + TILE - 1) / TILE, 256, 0, stream>>>(fbf, wbf, table, idx, bias, out, n);
}

// Round 12
// 303.839 us; speedup vs baseline: 1.1725x; 1.0117x over previous
//
#include <hip/hip_runtime.h>

#define VOL   2097152          // 128*128*128
#define TBL   4194304          // BATCH * VOL
#define D1D2  16384
#define DD2   128
#define TILE  128
#define ZOFF  (-40960)         // byte offset (from fbf) of the 128B zero row in wbf slack

typedef __bf16 bf16_t;
typedef bf16_t bf16x8 __attribute__((ext_vector_type(8)));
typedef float  floatx4 __attribute__((ext_vector_type(4)));

// ---------------- fused prep kernel ----------------
// block roles: [0, tblB) build table; [tblB, tblB+432) weight cvt;
//              [tblB+432, ...) feature cvt (original order) + zero-row init.
// table must be memset to -1 before this dispatch (stream-ordered).

__global__ __launch_bounds__(256) void prep_k(const float* __restrict__ f,
                                              const float* __restrict__ w,
                                              const int* __restrict__ idx,
                                              int* __restrict__ table,
                                              bf16_t* __restrict__ wb,
                                              bf16_t* __restrict__ fb, int n) {
    const int b = blockIdx.x;
    const int tblB = (n + 255) >> 8;
    if (b < tblB) {
        int t = b * 256 + threadIdx.x;
        if (t < n) {
            int4 c = ((const int4*)idx)[t];                 // b, i0, i1, i2
            int p = ((c.x * 128 + c.y) * 128 + c.z) * 128 + c.w;
            table[p] = t;                                   // original voxel id
        }
    } else if (b < tblB + 432) {
        int t = (b - tblB) * 256 + threadIdx.x;
        if (t < 27 * 64 * 64) {                             // [co][27][ci] -> [k][co][ci]
            int ci = t & 63, co = (t >> 6) & 63, k = t >> 12;
            wb[t] = (bf16_t)w[(co * 27 + k) * 64 + ci];
        }
    } else {
        int t = (b - tblB - 432) * 256 + threadIdx.x;       // unit = (voxel, 8-ch)
        int pos = t >> 3, c = (t & 7) * 8;
        if (pos < n) {
            const float* src = f + (size_t)pos * 64 + c;
            float4 a  = *(const float4*)src;
            float4 b2 = *(const float4*)(src + 4);
            bf16x8 o = { (bf16_t)a.x,  (bf16_t)a.y,  (bf16_t)a.z,  (bf16_t)a.w,
                         (bf16_t)b2.x, (bf16_t)b2.y, (bf16_t)b2.z, (bf16_t)b2.w };
            *(bf16x8*)(fb + (size_t)pos * 64 + c) = o;
        } else if (pos == n) {
            // zero row for missing neighbors: 128B in wbf slack, 8 thr x 16B
            bf16x8 z = {};
            *(bf16x8*)(wb + 110592 + c) = z;                // 110592 bf16 = byte 221184
        }
    }
}

// ---------------- main conv kernel (asm loads + counted vmcnt) ----------------
// block = 256 thr = 4 waves; tile = 128 voxels x 64 out-ch
// wave w: wc = w&1 -> co half; wv = w>>1 -> voxel half. 2 m-tiles x 4 n-groups x 2 k.
// s_off holds BYTE offsets into fbf; misses -> 128B zero row (ZOFF).
// ROUND-11 LESSON: sched_barrier alone can't preserve a register pipeline —
// SelectionDAG pre-sinks loads before the fences apply (VGPR 96 not ~190).
// FIX (HK/AITER pattern): loads are asm volatile global_load_dwordx4 (order
// and liveness forced at every compiler stage), waits are explicit counted
// s_waitcnt vmcnt(24) = "2 taps in flight" (12 loads/tap), with
// sched_barrier(0) after each wait so MFMAs can't hoist past it (rule #18).
// 3-deep rotation bA/bB/bC, aA/aB/aC; tail phases drain vmcnt 12 -> 0.
// __launch_bounds__(256,2): VGPR cap 256 (demand ~200, 2 waves/SIMD).
// mfma_f32_16x16x32_bf16: D col=lane&15, row=(lane>>4)*4+reg (m89/m91-verified)

#define GL16(dst, ptr) \
    asm volatile("global_load_dwordx4 %0, %1, off" : "=v"(dst) : "v"(ptr))

#define LOADB(KK, B) {                                                  \
    const int* sr = &s_off[(KK) * TILE + nrow];                         \
    int o0 = sr[0], o1 = sr[16], o2 = sr[32], o3 = sr[48];              \
    GL16(B[0], fB_ + o0);  GL16(B[1], fB_ + o0 + 64);                   \
    GL16(B[2], fB_ + o1);  GL16(B[3], fB_ + o1 + 64);                   \
    GL16(B[4], fB_ + o2);  GL16(B[5], fB_ + o2 + 64);                   \
    GL16(B[6], fB_ + o3);  GL16(B[7], fB_ + o3 + 64);                   \
}

#define LOADA(KK, A) {                                                  \
    const char* wk = wbase_b + (size_t)(KK) * 8192;                     \
    GL16(A[0], wk);        GL16(A[1], wk + 64);                         \
    GL16(A[2], wk + 2048); GL16(A[3], wk + 2112);                       \
}

#define DOMFMA(A, B) {                                                  \
    _Pragma("unroll")                                                   \
    for (int g = 0; g < 4; ++g) {                                       \
        acc[0][g] = __builtin_amdgcn_mfma_f32_16x16x32_bf16(A[0], B[2*g],   acc[0][g], 0, 0, 0); \
        acc[0][g] = __builtin_amdgcn_mfma_f32_16x16x32_bf16(A[1], B[2*g+1], acc[0][g], 0, 0, 0); \
        acc[1][g] = __builtin_amdgcn_mfma_f32_16x16x32_bf16(A[2], B[2*g],   acc[1][g], 0, 0, 0); \
        acc[1][g] = __builtin_amdgcn_mfma_f32_16x16x32_bf16(A[3], B[2*g+1], acc[1][g], 0, 0, 0); \
    }                                                                   \
}

#define SB() __builtin_amdgcn_sched_barrier(0)
#define VMW(N) asm volatile("s_waitcnt vmcnt(" #N ")" ::: "memory")

__global__ __launch_bounds__(256, 2) void conv_k(
        const bf16_t* __restrict__ fb, const bf16_t* __restrict__ wb,
        const int* __restrict__ table, const int* __restrict__ idx,
        const float* __restrict__ bias, float* __restrict__ out, int n)
{
    __shared__ int s_pkd[TILE];
    __shared__ int s_shift[32];
    __shared__ int s_off[27 * TILE];   // BYTE offsets into fbf (ZOFF = miss)

    const int t    = threadIdx.x;
    const int tile = blockIdx.x * TILE;

    if (t < 27) {
        int k0 = t / 9, k1 = (t / 3) % 3, k2 = t % 3;
        s_shift[t] = (k0 - 1) * D1D2 + (k1 - 1) * DD2 + (k2 - 1);
    }
    if (t < TILE) {
        int vn = tile + t;
        if (vn < n) {
            int4 c = ((const int4*)idx)[vn];
            s_pkd[t] = ((c.x * 128 + c.y) * 128 + c.z) * 128 + c.w;
        } else {
            s_pkd[t] = (int)0xC0000000;   // sentinel: all taps miss
        }
    }
    __syncthreads();

    for (int u = t; u < 27 * TILE; u += 256) {
        int k  = u >> 7;                  // TILE == 128
        int r  = u & (TILE - 1);
        int np = s_pkd[r] + s_shift[k];
        int v  = (np >= 0 && np < TBL) ? table[np] : -1;
        s_off[u] = (v >= 0) ? (v << 7) : ZOFF;   // byte offset of feature row
    }

    const int lane = t & 63;
    const int w    = t >> 6;
    const int wc   = w & 1;               // co half
    const int wv   = w >> 1;              // voxel half
    const int l15  = lane & 15;
    const int q    = lane >> 4;

    __syncthreads();                      // s_off ready — LAST barrier in kernel

    // per-lane bases: fold q*16 bytes into feature base; A: co=wc*32+l15, ci=q*8
    const char* fB_     = (const char*)fb + q * 16;
    const char* wbase_b = (const char*)(wb + (size_t)(wc * 32 + l15) * 64 + q * 8);
    const int   nrow    = wv * 64 + l15;  // this lane's voxel row within tile

    floatx4 acc[2][4] = {};
    bf16x8 bA[8], bB[8], bC[8], aA[4], aB[4], aC[4];

    // prologue: taps 0,1 in flight (24 loads)
    LOADB(0, bA); LOADA(0, aA);
    LOADB(1, bB); LOADA(1, aB);

    #pragma unroll
    for (int k = 0; k < 24; k += 3) {     // phases 0..23: loads taps 2..25
        LOADB(k + 2, bC); LOADA(k + 2, aC);
        SB(); VMW(24); SB();
        DOMFMA(aA, bA);                   // tap k
        SB();
        LOADB(k + 3, bA); LOADA(k + 3, aA);
        SB(); VMW(24); SB();
        DOMFMA(aB, bB);                   // tap k+1
        SB();
        LOADB(k + 4, bB); LOADA(k + 4, aB);
        SB(); VMW(24); SB();
        DOMFMA(aC, bC);                   // tap k+2
        SB();
    }
    // tail: phase 24 (load tap 26), 25, 26 — drain vmcnt 24 -> 12 -> 0
    LOADB(26, bC); LOADA(26, aC);
    SB(); VMW(24); SB();
    DOMFMA(aA, bA);                       // tap 24
    SB(); VMW(12); SB();
    DOMFMA(aB, bB);                       // tap 25
    SB(); VMW(0);  SB();
    DOMFMA(aC, bC);                       // tap 26
    SB();

    // epilogue: co = wc*32 + m*16 + q*4 + reg, voxel = tile + wv*64 + g*16 + l15
    const float4 bs0 = *(const float4*)&bias[wc * 32 + q * 4];
    const float4 bs1 = *(const float4*)&bias[wc * 32 + 16 + q * 4];
    #pragma unroll
    for (int g = 0; g < 4; ++g) {
        int vn = tile + wv * 64 + g * 16 + l15;
        if (vn < n) {
            float4 o0, o1;
            o0.x = acc[0][g][0] + bs0.x;
            o0.y = acc[0][g][1] + bs0.y;
            o0.z = acc[0][g][2] + bs0.z;
            o0.w = acc[0][g][3] + bs0.w;
            o1.x = acc[1][g][0] + bs1.x;
            o1.y = acc[1][g][1] + bs1.y;
            o1.z = acc[1][g][2] + bs1.z;
            o1.w = acc[1][g][3] + bs1.w;
            float* dst = &out[(size_t)vn * 64 + wc * 32 + q * 4];
            *(float4*)dst        = o0;
            *(float4*)(dst + 16) = o1;
        }
    }
}

// ---------------- launch ----------------

extern "C" void kernel_launch(void* const* d_in, const int* in_sizes, int n_in,
                              void* d_out, int out_size, void* d_ws, size_t ws_size,
                              hipStream_t stream) {
    const float* feat = (const float*)d_in[0];
    const float* wgt  = (const float*)d_in[1];
    const float* bias = (const float*)d_in[2];
    const int*   idx  = (const int*)d_in[3];
    float* out = (float*)d_out;

    const int n = in_sizes[0] / 64;          // active voxels

    // ws layout (round-1 proven, 50.6 MB): [table 16MB][wbf 256KB][fbf 33.5MB]
    // zero row lives in wbf slack: byte 221184..221312 (= fbf + ZOFF)
    char* ws = (char*)d_ws;
    int*    table = (int*)ws;
    bf16_t* wbf   = (bf16_t*)(ws + (size_t)TBL * 4);
    bf16_t* fbf   = (bf16_t*)(ws + (size_t)TBL * 4 + 262144);

    hipMemsetAsync(table, 0xFF, (size_t)TBL * 4, stream);   // all -1

    int tblB = (n + 255) >> 8;
    int fB   = (n * 8 + 255) >> 8;
    // +1 block: zero-row init rides the feature section (pos == n)
    prep_k<<<tblB + 432 + fB + 1, 256, 0, stream>>>(feat, wgt, idx, table, wbf, fbf, n);

    conv_k<<<(n + TILE - 1) / TILE, 256, 0, stream>>>(fbf, wbf, table, idx, bias, out, n);
}